// Round 7
// baseline (419.916 us; speedup 1.0000x reference)
//
#include <hip/hip_runtime.h>

#define N_NODES 50000
#define N_EDGES 500000
#define F_DIM 256
#define ED_DIM 64
#define H_DIM 128
#define O_DIM 32
#define NEG_SLOPE 0.2f
#define EPS_F 1e-16f

#define EB 2048          // edge kernel blocks
#define AGG_REP 2        // DIAGNOSTIC: run agg bodies twice (idempotent) for attribution

typedef __attribute__((ext_vector_type(8))) short short8;
typedef __attribute__((ext_vector_type(4))) float floatx4;

__device__ __forceinline__ unsigned short f2bf(float f) {
    union { float f; unsigned u; } c; c.f = f;
    unsigned u = c.u;
    return (unsigned short)((u + 0x7fffu + ((u >> 16) & 1u)) >> 16);
}
__device__ __forceinline__ float bf2f_lo(unsigned u) { return __uint_as_float(u << 16); }
__device__ __forceinline__ float bf2f_hi(unsigned u) { return __uint_as_float(u & 0xffff0000u); }
__device__ __forceinline__ float leaky(float a) { return a > 0.f ? a : a * NEG_SLOPE; }
__device__ __forceinline__ float dot4(float4 a, float4 b) {
    return a.x * b.x + a.y * b.y + a.z * b.z + a.w * b.w;
}

// ---- prep: wv = We@a_edge, was2/wad2 = W2@att2, W transposes, zero cnt ----
__global__ void k_prep(const float* __restrict__ We1, const float* __restrict__ aev1,
                       const float* __restrict__ We2, const float* __restrict__ aev2,
                       float* __restrict__ wv1, float* __restrict__ wv2,
                       const float* __restrict__ W1, const float* __restrict__ W2,
                       const float* __restrict__ as2v, const float* __restrict__ ad2v,
                       float* __restrict__ was2, float* __restrict__ wad2,
                       unsigned short* __restrict__ W1T, unsigned short* __restrict__ W2T,
                       int* __restrict__ cnt) {
    if (blockIdx.x == 32) {
        int t = threadIdx.x;
        if (t < 64) {
            float s = 0.f;
            for (int c = 0; c < H_DIM; c++) s += We1[t * H_DIM + c] * aev1[c];
            wv1[t] = s;
        } else if (t < 128) {
            int k = t - 64;
            float s = 0.f;
            for (int c = 0; c < O_DIM; c++) s += We2[k * O_DIM + c] * aev2[c];
            wv2[k] = s;
        } else {
            int c = t - 128;   // 0..127
            float s = 0.f, d = 0.f;
            for (int o = 0; o < O_DIM; o++) {
                float w = W2[c * O_DIM + o];
                s += w * as2v[o];
                d += w * ad2v[o];
            }
            was2[c] = s; wad2[c] = d;
        }
        return;
    }
    int gid = blockIdx.x * 256 + threadIdx.x;
    const int stride = 32 * 256;
    for (int i = gid; i < N_NODES; i += stride) cnt[i] = 0;
    for (int i = gid; i < H_DIM * F_DIM; i += stride) {
        int n = i >> 8, k = i & 255;
        W1T[i] = f2bf(W1[k * H_DIM + n]);
    }
    for (int i = gid; i < O_DIM * H_DIM; i += stride) {
        int n = i >> 7, k = i & 127;
        W2T[i] = f2bf(W2[k * O_DIM + n]);
    }
}

// ---- per-edge a_e: 4-lane subgroups, EDGE-PAIR unroll -> 8 loads in flight/lane ----
__global__ __launch_bounds__(256) void k_edge_ae(
        const float* __restrict__ ea, const int* __restrict__ dst,
        const float* __restrict__ wv1, const float* __restrict__ wv2,
        float2* __restrict__ ae12, int* __restrict__ cnt) {
    int tid = threadIdx.x;
    int wave = tid >> 6, lane = tid & 63;
    int sub = lane & 3, eg = lane >> 2;
    float4 w1[4], w2[4];
#pragma unroll
    for (int j = 0; j < 4; j++) {
        w1[j] = ((const float4*)wv1)[sub * 4 + j];
        w2[j] = ((const float4*)wv2)[sub * 4 + j];
    }
    // each subgroup owns an even-aligned edge PAIR; N_EDGES is even
    int e0 = ((blockIdx.x * 4 + wave) * 16 + eg) * 2;
    const int stride = EB * 128;
    for (int e = e0; e < N_EDGES; e += stride) {
        const float4* r0 = (const float4*)(ea + (size_t)e * ED_DIM + sub * 16);
        const float4* r1 = (const float4*)(ea + (size_t)(e + 1) * ED_DIM + sub * 16);
        float4 a0 = r0[0], a1 = r0[1], a2 = r0[2], a3 = r0[3];
        float4 b0 = r1[0], b1 = r1[1], b2 = r1[2], b3 = r1[3];
        float s1 = dot4(a0, w1[0]) + dot4(a1, w1[1]) + dot4(a2, w1[2]) + dot4(a3, w1[3]);
        float s2 = dot4(a0, w2[0]) + dot4(a1, w2[1]) + dot4(a2, w2[2]) + dot4(a3, w2[3]);
        float t1 = dot4(b0, w1[0]) + dot4(b1, w1[1]) + dot4(b2, w1[2]) + dot4(b3, w1[3]);
        float t2 = dot4(b0, w2[0]) + dot4(b1, w2[1]) + dot4(b2, w2[2]) + dot4(b3, w2[3]);
        s1 += __shfl_xor(s1, 1); s2 += __shfl_xor(s2, 1);
        t1 += __shfl_xor(t1, 1); t2 += __shfl_xor(t2, 1);
        s1 += __shfl_xor(s1, 2); s2 += __shfl_xor(s2, 2);
        t1 += __shfl_xor(t1, 2); t2 += __shfl_xor(t2, 2);
        if (sub == 0) {
            ae12[e] = make_float2(s1, s2);
            ae12[e + 1] = make_float2(t1, t2);
            atomicAdd(&cnt[dst[e]], 1);
            atomicAdd(&cnt[dst[e + 1]], 1);
        }
    }
}

// ======= MFMA GEMM layer 1: h1(bf16) = x@W1, fused a_s/a_d =======
__global__ __launch_bounds__(256) void k_gemm1(const float* __restrict__ A,
        const unsigned short* __restrict__ BT,
        const float* __restrict__ asv, const float* __restrict__ adv,
        unsigned short* __restrict__ Hb, float* __restrict__ a_s, float* __restrict__ a_d, int M) {
    __shared__ unsigned short As[128 * 40];
    __shared__ unsigned short Bs[128 * 40];
    int tid = threadIdx.x;
    int wave = tid >> 6, lane = tid & 63;
    int q = lane >> 4, r = lane & 15;
    int bm0 = blockIdx.x * 128;
    floatx4 acc[2][8];
#pragma unroll
    for (int a = 0; a < 2; a++)
#pragma unroll
        for (int b = 0; b < 8; b++) acc[a][b] = (floatx4){0.f, 0.f, 0.f, 0.f};

    int rr = tid >> 3;
    int kc = tid & 7;
    for (int k0 = 0; k0 < 256; k0 += 32) {
#pragma unroll
        for (int i = 0; i < 4; i++) {
            int row = rr + 32 * i;
            int gr = bm0 + row;
            float4 v = make_float4(0.f, 0.f, 0.f, 0.f);
            if (gr < M) v = *(const float4*)(A + (size_t)gr * 256 + k0 + kc * 4);
            unsigned lo = (unsigned)f2bf(v.x) | ((unsigned)f2bf(v.y) << 16);
            unsigned hi = (unsigned)f2bf(v.z) | ((unsigned)f2bf(v.w) << 16);
            *(uint2*)&As[row * 40 + kc * 4] = make_uint2(lo, hi);
        }
#pragma unroll
        for (int i = 0; i < 2; i++) {
            int idx = tid + 256 * i;
            int n = idx >> 2, ck = idx & 3;
            *(uint4*)&Bs[n * 40 + ck * 8] = *(const uint4*)(BT + n * 256 + k0 + ck * 8);
        }
        __syncthreads();
        short8 af[2], bf[8];
#pragma unroll
        for (int rt = 0; rt < 2; rt++)
            af[rt] = *(const short8*)&As[(wave * 32 + rt * 16 + r) * 40 + q * 8];
#pragma unroll
        for (int nt = 0; nt < 8; nt++)
            bf[nt] = *(const short8*)&Bs[(nt * 16 + r) * 40 + q * 8];
#pragma unroll
        for (int rt = 0; rt < 2; rt++)
#pragma unroll
            for (int nt = 0; nt < 8; nt++)
                acc[rt][nt] = __builtin_amdgcn_mfma_f32_16x16x32_bf16(af[rt], bf[nt], acc[rt][nt], 0, 0, 0);
        __syncthreads();
    }
#pragma unroll
    for (int rt = 0; rt < 2; rt++) {
        int rowb = bm0 + wave * 32 + rt * 16 + q * 4;
        float ps[4] = {0.f, 0.f, 0.f, 0.f}, pd[4] = {0.f, 0.f, 0.f, 0.f};
#pragma unroll
        for (int nt = 0; nt < 8; nt++) {
            int col = nt * 16 + r;
            float av = asv[col], dv = adv[col];
#pragma unroll
            for (int reg = 0; reg < 4; reg++) {
                float v = acc[rt][nt][reg];
                if (rowb + reg < M) Hb[(size_t)(rowb + reg) * 128 + col] = f2bf(v);
                ps[reg] += v * av;
                pd[reg] += v * dv;
            }
        }
#pragma unroll
        for (int reg = 0; reg < 4; reg++) {
#pragma unroll
            for (int off = 1; off < 16; off <<= 1) {
                ps[reg] += __shfl_xor(ps[reg], off);
                pd[reg] += __shfl_xor(pd[reg], off);
            }
        }
        if (r == 0) {
#pragma unroll
            for (int reg = 0; reg < 4; reg++) {
                if (rowb + reg < M) { a_s[rowb + reg] = ps[reg]; a_d[rowb + reg] = pd[reg]; }
            }
        }
    }
}

// ---------------- prefix-sum (CSR offsets), 2 dispatches ----------------
__global__ void k_scan1(const int* __restrict__ cnt, int* __restrict__ bsum, int n) {
    __shared__ int sh[256];
    int b = blockIdx.x, t = threadIdx.x;
    int base = b * 1024;
    int s = 0;
    for (int j = 0; j < 4; j++) {
        int idx = base + t * 4 + j;
        if (idx < n) s += cnt[idx];
    }
    sh[t] = s; __syncthreads();
    for (int o = 128; o > 0; o >>= 1) {
        if (t < o) sh[t] += sh[t + o];
        __syncthreads();
    }
    if (t == 0) bsum[b] = sh[0];
}

// per-block bsum prefix computed in-kernel (nb <= 64)
__global__ void k_scan3(const int* __restrict__ cnt, const int* __restrict__ bsum,
                        int* __restrict__ offs, int* __restrict__ cursor, int n, int nb) {
    __shared__ int sh[256];
    __shared__ int bpre_sh;
    int b = blockIdx.x, t = threadIdx.x;
    if (t < 64) {
        int v = (t < b) ? bsum[t] : 0;
#pragma unroll
        for (int o = 1; o < 64; o <<= 1) v += __shfl_xor(v, o);
        if (t == 0) bpre_sh = v;
    }
    int base = b * 1024;
    int v4[4]; int s = 0;
    for (int j = 0; j < 4; j++) {
        int idx = base + t * 4 + j;
        v4[j] = (idx < n) ? cnt[idx] : 0;
        s += v4[j];
    }
    sh[t] = s; __syncthreads();
    for (int o = 1; o < 256; o <<= 1) {
        int x = (t >= o) ? sh[t - o] : 0;
        __syncthreads();
        sh[t] += x;
        __syncthreads();
    }
    int texcl = sh[t] - s + bpre_sh;
    int run = 0;
    for (int j = 0; j < 4; j++) {
        int idx = base + t * 4 + j;
        if (idx < n) { offs[idx] = texcl + run; cursor[idx] = texcl + run; }
        run += v4[j];
    }
    if (b == nb - 1 && t == 255) offs[n] = bpre_sh + sh[255];
}

// scatter edges into CSR order; packed entry {src, ae1, ae2, a_s1[src]} (one 16B line)
__global__ __launch_bounds__(256) void k_scatter(const int* __restrict__ src, const int* __restrict__ dst,
                          const float2* __restrict__ ae12, const float* __restrict__ a_s1,
                          int* __restrict__ cursor, float4* __restrict__ csr) {
    int e = blockIdx.x * blockDim.x + threadIdx.x;
    if (e >= N_EDGES) return;
    int s = src[e];
    int d = dst[e];
    float2 a = ae12[e];
    float as = a_s1[s];
    int p = atomicAdd(&cursor[d], 1);
    csr[p] = make_float4(__int_as_float(s), a.x, a.y, as);
}

// ========== single-pass softmax agg C=128 (bf16 gather), fused a_s2/a_d2 ==========
// DIAGNOSTIC: AGG_REP repeats of an idempotent body (memory clobber stops collapse)
template <bool RELU>
__global__ __launch_bounds__(256) void k_agg128(const unsigned short* __restrict__ h,
                         const float* __restrict__ a_s, const float* __restrict__ a_d,
                         const int* __restrict__ offs, const float4* __restrict__ csr,
                         const float* __restrict__ bias,
                         const float* __restrict__ was2, const float* __restrict__ wad2,
                         float* __restrict__ a_s2, float* __restrict__ a_d2,
                         float* __restrict__ out) {
    int wave = threadIdx.x >> 6, lane = threadIdx.x & 63;
    int i = blockIdx.x * 4 + wave;
    int r = lane & 15;       // channel group: channels r*8 .. r*8+7
    int g = lane >> 4;       // edge subgroup (4 subgroups of 16)

#define P128(EL)                                                              \
    {                                                                         \
        float4 c = csr[EL];            /* uniform addr in subgroup: L1 bcast */\
        int s = __float_as_int(c.x);                                          \
        float aev = c.y;                                                      \
        float ex = __expf(leaky(c.w + adl + aev));                            \
        if (r == 0) { dsum += ex; sum_ae += aev; }                            \
        uint4 hv = *(const uint4*)(h + (size_t)s * 128 + r * 8);              \
        acc0.x += ex * bf2f_lo(hv.x); acc0.y += ex * bf2f_hi(hv.x);           \
        acc0.z += ex * bf2f_lo(hv.y); acc0.w += ex * bf2f_hi(hv.y);           \
        acc1.x += ex * bf2f_lo(hv.z); acc1.y += ex * bf2f_hi(hv.z);           \
        acc1.z += ex * bf2f_lo(hv.w); acc1.w += ex * bf2f_hi(hv.w);           \
    }

    for (int rep = 0; rep < AGG_REP; rep++) {
        asm volatile("" ::: "memory");   // forbid loop-invariant collapse of reps
        int rs = offs[i], re = offs[i + 1];
        int deg = re - rs;
        float adl = a_d[i];
        float4 acc0 = {0.f, 0.f, 0.f, 0.f}, acc1 = {0.f, 0.f, 0.f, 0.f};
        float dsum = 0.f, sum_ae = 0.f;

        int el = rs + g;
        for (; el + 4 < re; el += 8) { P128(el); P128(el + 4); }
        if (el < re) P128(el);

        // dsum/sum_ae nonzero only in lanes 0,16,32,48 -> FULL butterfly broadcast
#pragma unroll
        for (int o = 1; o < 64; o <<= 1) {
            dsum += __shfl_xor(dsum, o);
            sum_ae += __shfl_xor(sum_ae, o);
        }

        float loop_ae = sum_ae / (float)(deg > 1 ? deg : 1);
        float al = leaky(a_s[i] + adl + loop_ae);
        float exs = __expf(al);
        float* a0 = (float*)&acc0; float* a1 = (float*)&acc1;
#pragma unroll
        for (int c = 0; c < 4; c++) {
            a0[c] += __shfl_xor(a0[c], 16); a0[c] += __shfl_xor(a0[c], 32);
            a1[c] += __shfl_xor(a1[c], 16); a1[c] += __shfl_xor(a1[c], 32);
        }
        if (g == 0) {
            float inv = 1.0f / (dsum + exs + EPS_F);
            uint4 hv = *(const uint4*)(h + (size_t)i * 128 + r * 8);
            const float4* bp = (const float4*)bias;
            float4 b0 = bp[r * 2], b1 = bp[r * 2 + 1];
            float4 o0, o1;
            o0.x = (a0[0] + exs * bf2f_lo(hv.x)) * inv + b0.x;
            o0.y = (a0[1] + exs * bf2f_hi(hv.x)) * inv + b0.y;
            o0.z = (a0[2] + exs * bf2f_lo(hv.y)) * inv + b0.z;
            o0.w = (a0[3] + exs * bf2f_hi(hv.y)) * inv + b0.w;
            o1.x = (a1[0] + exs * bf2f_lo(hv.z)) * inv + b1.x;
            o1.y = (a1[1] + exs * bf2f_hi(hv.z)) * inv + b1.y;
            o1.z = (a1[2] + exs * bf2f_lo(hv.w)) * inv + b1.z;
            o1.w = (a1[3] + exs * bf2f_hi(hv.w)) * inv + b1.w;
            if (RELU) {
                o0.x = fmaxf(o0.x, 0.f); o0.y = fmaxf(o0.y, 0.f); o0.z = fmaxf(o0.z, 0.f); o0.w = fmaxf(o0.w, 0.f);
                o1.x = fmaxf(o1.x, 0.f); o1.y = fmaxf(o1.y, 0.f); o1.z = fmaxf(o1.z, 0.f); o1.w = fmaxf(o1.w, 0.f);
            }
            float4* op = (float4*)(out + (size_t)i * 128);
            op[r * 2] = o0;
            op[r * 2 + 1] = o1;
            // fused layer-2 attention scalars: a_s2 = x~ . (W2@att_src2), f32-exact
            float4 wsa = ((const float4*)was2)[r * 2], wsb = ((const float4*)was2)[r * 2 + 1];
            float4 wda = ((const float4*)wad2)[r * 2], wdb = ((const float4*)wad2)[r * 2 + 1];
            float ps = dot4(o0, wsa) + dot4(o1, wsb);
            float pd = dot4(o0, wda) + dot4(o1, wdb);
#pragma unroll
            for (int o = 1; o < 16; o <<= 1) {
                ps += __shfl_xor(ps, o);
                pd += __shfl_xor(pd, o);
            }
            if (r == 0) { a_s2[i] = ps; a_d2[i] = pd; }
        }
    }
#undef P128
}

// =============== MFMA GEMM layer 2: h2(bf16) = relu(x1)@W2 ===============
__global__ __launch_bounds__(256) void k_gemm2(const float* __restrict__ A,
        const unsigned short* __restrict__ BT,
        unsigned short* __restrict__ Hb, int M) {
    __shared__ unsigned short As[128 * 40];
    __shared__ unsigned short Bs[32 * 40];
    int tid = threadIdx.x;
    int wave = tid >> 6, lane = tid & 63;
    int q = lane >> 4, r = lane & 15;
    int bm0 = blockIdx.x * 128;
    floatx4 acc[2][2];
#pragma unroll
    for (int a = 0; a < 2; a++)
#pragma unroll
        for (int b = 0; b < 2; b++) acc[a][b] = (floatx4){0.f, 0.f, 0.f, 0.f};

    int rr = tid >> 3;
    int kc = tid & 7;
    for (int k0 = 0; k0 < 128; k0 += 32) {
#pragma unroll
        for (int i = 0; i < 4; i++) {
            int row = rr + 32 * i;
            int gr = bm0 + row;
            float4 v = make_float4(0.f, 0.f, 0.f, 0.f);
            if (gr < M) v = *(const float4*)(A + (size_t)gr * 128 + k0 + kc * 4);
            unsigned lo = (unsigned)f2bf(v.x) | ((unsigned)f2bf(v.y) << 16);
            unsigned hi = (unsigned)f2bf(v.z) | ((unsigned)f2bf(v.w) << 16);
            *(uint2*)&As[row * 40 + kc * 4] = make_uint2(lo, hi);
        }
        if (tid < 128) {
            int n = tid >> 2, ck = tid & 3;
            *(uint4*)&Bs[n * 40 + ck * 8] = *(const uint4*)(BT + n * 128 + k0 + ck * 8);
        }
        __syncthreads();
        short8 af[2], bf[2];
#pragma unroll
        for (int rt = 0; rt < 2; rt++)
            af[rt] = *(const short8*)&As[(wave * 32 + rt * 16 + r) * 40 + q * 8];
#pragma unroll
        for (int nt = 0; nt < 2; nt++)
            bf[nt] = *(const short8*)&Bs[(nt * 16 + r) * 40 + q * 8];
#pragma unroll
        for (int rt = 0; rt < 2; rt++)
#pragma unroll
            for (int nt = 0; nt < 2; nt++)
                acc[rt][nt] = __builtin_amdgcn_mfma_f32_16x16x32_bf16(af[rt], bf[nt], acc[rt][nt], 0, 0, 0);
        __syncthreads();
    }
#pragma unroll
    for (int rt = 0; rt < 2; rt++) {
        int rowb = bm0 + wave * 32 + rt * 16 + q * 4;
#pragma unroll
        for (int nt = 0; nt < 2; nt++) {
            int col = nt * 16 + r;
#pragma unroll
            for (int reg = 0; reg < 4; reg++) {
                if (rowb + reg < M) Hb[(size_t)(rowb + reg) * 32 + col] = f2bf(acc[rt][nt][reg]);
            }
        }
    }
}

// ========== single-pass softmax agg C=32 (bf16 gather), 8-lane subgroups ==========
__global__ __launch_bounds__(256) void k_agg32(const unsigned short* __restrict__ h,
                        const float* __restrict__ a_s, const float* __restrict__ a_d,
                        const int* __restrict__ offs, const float4* __restrict__ csr,
                        const float* __restrict__ bias,
                        float* __restrict__ out) {
    int wave = threadIdx.x >> 6, lane = threadIdx.x & 63;
    int i = blockIdx.x * 4 + wave;
    int r = lane & 7;        // channels r*4 .. r*4+3
    int g = lane >> 3;       // 8 edge subgroups

#define P32(EL)                                                               \
    {                                                                         \
        float4 c = csr[EL];                                                   \
        int s = __float_as_int(c.x);                                          \
        float aev = c.z;                                                      \
        float ex = __expf(leaky(a_s[s] + adl + aev));                         \
        if (r == 0) { dsum += ex; sum_ae += aev; }                            \
        uint2 hv = *(const uint2*)(h + (size_t)s * 32 + r * 4);               \
        acc.x += ex * bf2f_lo(hv.x); acc.y += ex * bf2f_hi(hv.x);             \
        acc.z += ex * bf2f_lo(hv.y); acc.w += ex * bf2f_hi(hv.y);             \
    }

    for (int rep = 0; rep < AGG_REP; rep++) {
        asm volatile("" ::: "memory");   // forbid loop-invariant collapse of reps
        int rs = offs[i], re = offs[i + 1];
        int deg = re - rs;
        float adl = a_d[i];
        float4 acc = {0.f, 0.f, 0.f, 0.f};
        float dsum = 0.f, sum_ae = 0.f;

        int el = rs + g;
        for (; el + 8 < re; el += 16) { P32(el); P32(el + 8); }
        if (el < re) P32(el);

        // dsum/sum_ae nonzero only in lanes 0,8,...,56 -> FULL butterfly broadcast
#pragma unroll
        for (int o = 1; o < 64; o <<= 1) {
            dsum += __shfl_xor(dsum, o);
            sum_ae += __shfl_xor(sum_ae, o);
        }

        float loop_ae = sum_ae / (float)(deg > 1 ? deg : 1);
        float al = leaky(a_s[i] + adl + loop_ae);
        float exs = __expf(al);
#pragma unroll
        for (int o = 8; o < 64; o <<= 1) {
            acc.x += __shfl_xor(acc.x, o); acc.y += __shfl_xor(acc.y, o);
            acc.z += __shfl_xor(acc.z, o); acc.w += __shfl_xor(acc.w, o);
        }
        if (g == 0) {
            float inv = 1.0f / (dsum + exs + EPS_F);
            uint2 hv = *(const uint2*)(h + (size_t)i * 32 + r * 4);
            float4 bv = ((const float4*)bias)[r];
            float4 ov;
            ov.x = (acc.x + exs * bf2f_lo(hv.x)) * inv + bv.x;
            ov.y = (acc.y + exs * bf2f_hi(hv.x)) * inv + bv.y;
            ov.z = (acc.z + exs * bf2f_lo(hv.y)) * inv + bv.z;
            ov.w = (acc.w + exs * bf2f_hi(hv.y)) * inv + bv.w;
            ((float4*)(out + (size_t)i * 32))[r] = ov;
        }
    }
#undef P32
}

extern "C" void kernel_launch(void* const* d_in, const int* in_sizes, int n_in,
                              void* d_out, int out_size, void* d_ws, size_t ws_size,
                              hipStream_t stream) {
    const float* x    = (const float*)d_in[0];
    const int* ei     = (const int*)d_in[1];
    const float* ea   = (const float*)d_in[2];
    const float* W1   = (const float*)d_in[3];
    const float* as1v = (const float*)d_in[4];
    const float* ad1v = (const float*)d_in[5];
    const float* We1  = (const float*)d_in[6];
    const float* aev1 = (const float*)d_in[7];
    const float* b1   = (const float*)d_in[8];
    const float* W2   = (const float*)d_in[9];
    const float* as2v = (const float*)d_in[10];
    const float* ad2v = (const float*)d_in[11];
    const float* We2  = (const float*)d_in[12];
    const float* aev2 = (const float*)d_in[13];
    const float* b2   = (const float*)d_in[14];

    const int* src = ei;
    const int* dst = ei + N_EDGES;

    char* w = (char*)d_ws;
    size_t off = 0;
    auto alloc = [&](size_t bytes) -> void* {
        void* p = w + off;
        off += bytes;
        off = (off + 255) & ~(size_t)255;
        return p;
    };
    unsigned short* h1b = (unsigned short*)alloc((size_t)N_NODES * H_DIM * 2);
    unsigned short* h2b = (unsigned short*)alloc((size_t)N_NODES * O_DIM * 2);
    float2* ae12   = (float2*)alloc((size_t)N_EDGES * 8);
    int* cnt       = (int*)alloc((size_t)N_NODES * 4);
    int* offs      = (int*)alloc((size_t)(N_NODES + 1) * 4);
    int* cursor    = (int*)alloc((size_t)N_NODES * 4);
    float4* csr    = (float4*)alloc((size_t)N_EDGES * 16);
    int* bsum      = (int*)alloc(64 * 4);
    float* wv1     = (float*)alloc(64 * 4);
    float* wv2     = (float*)alloc(64 * 4);
    float* was2    = (float*)alloc(128 * 4);
    float* wad2    = (float*)alloc(128 * 4);
    float* a_s1    = (float*)alloc((size_t)N_NODES * 4);
    float* a_d1    = (float*)alloc((size_t)N_NODES * 4);
    float* a_s2    = (float*)alloc((size_t)N_NODES * 4);
    float* a_d2    = (float*)alloc((size_t)N_NODES * 4);
    unsigned short* W1T = (unsigned short*)alloc((size_t)H_DIM * F_DIM * 2);
    unsigned short* W2T = (unsigned short*)alloc((size_t)O_DIM * H_DIM * 2);

    k_prep<<<33, 256, 0, stream>>>(We1, aev1, We2, aev2, wv1, wv2, W1, W2,
                                   as2v, ad2v, was2, wad2, W1T, W2T, cnt);

    k_edge_ae<<<EB, 256, 0, stream>>>(ea, dst, wv1, wv2, ae12, cnt);

    k_gemm1<<<(N_NODES + 127) / 128, 256, 0, stream>>>(x, W1T, as1v, ad1v,
                                                       h1b, a_s1, a_d1, N_NODES);

    int nb = (N_NODES + 1023) / 1024;   // 49 (<= 64)
    k_scan1<<<nb, 256, 0, stream>>>(cnt, bsum, N_NODES);
    k_scan3<<<nb, 256, 0, stream>>>(cnt, bsum, offs, cursor, N_NODES, nb);

    k_scatter<<<(N_EDGES + 255) / 256, 256, 0, stream>>>(src, dst, ae12, a_s1,
                                                         cursor, csr);

    float* out = (float*)d_out;                       // [N, O]
    float* h_out = out + (size_t)N_NODES * O_DIM;     // [N, H] = relu(x1)

    k_agg128<true><<<(N_NODES + 3) / 4, 256, 0, stream>>>(h1b, a_s1, a_d1, offs,
                                                          csr, b1, was2, wad2,
                                                          a_s2, a_d2, h_out);

    k_gemm2<<<(N_NODES + 127) / 128, 256, 0, stream>>>(h_out, W2T, h2b, N_NODES);

    k_agg32<<<(N_NODES + 3) / 4, 256, 0, stream>>>(h2b, a_s2, a_d2, offs,
                                                   csr, b2, out);
}

// Round 8
// 402.413 us; speedup vs baseline: 1.0435x; 1.0435x over previous
//
#include <hip/hip_runtime.h>

#define N_NODES 50000
#define N_EDGES 500000
#define F_DIM 256
#define ED_DIM 64
#define H_DIM 128
#define O_DIM 32
#define NEG_SLOPE 0.2f
#define EPS_F 1e-16f

#define EB 2048          // edge kernel blocks
#define REP 2            // DIAGNOSTIC: double idempotent kernel bodies for attribution

typedef __attribute__((ext_vector_type(8))) short short8;
typedef __attribute__((ext_vector_type(4))) float floatx4;

__device__ __forceinline__ unsigned short f2bf(float f) {
    union { float f; unsigned u; } c; c.f = f;
    unsigned u = c.u;
    return (unsigned short)((u + 0x7fffu + ((u >> 16) & 1u)) >> 16);
}
__device__ __forceinline__ float bf2f_lo(unsigned u) { return __uint_as_float(u << 16); }
__device__ __forceinline__ float bf2f_hi(unsigned u) { return __uint_as_float(u & 0xffff0000u); }
__device__ __forceinline__ float leaky(float a) { return a > 0.f ? a : a * NEG_SLOPE; }
__device__ __forceinline__ float dot4(float4 a, float4 b) {
    return a.x * b.x + a.y * b.y + a.z * b.z + a.w * b.w;
}

// ---- prep: wv = We@a_edge, was2/wad2 = W2@att2, W transposes, zero cnt ----
__global__ void k_prep(const float* __restrict__ We1, const float* __restrict__ aev1,
                       const float* __restrict__ We2, const float* __restrict__ aev2,
                       float* __restrict__ wv1, float* __restrict__ wv2,
                       const float* __restrict__ W1, const float* __restrict__ W2,
                       const float* __restrict__ as2v, const float* __restrict__ ad2v,
                       float* __restrict__ was2, float* __restrict__ wad2,
                       unsigned short* __restrict__ W1T, unsigned short* __restrict__ W2T,
                       int* __restrict__ cnt) {
    if (blockIdx.x == 32) {
        int t = threadIdx.x;
        if (t < 64) {
            float s = 0.f;
            for (int c = 0; c < H_DIM; c++) s += We1[t * H_DIM + c] * aev1[c];
            wv1[t] = s;
        } else if (t < 128) {
            int k = t - 64;
            float s = 0.f;
            for (int c = 0; c < O_DIM; c++) s += We2[k * O_DIM + c] * aev2[c];
            wv2[k] = s;
        } else {
            int c = t - 128;   // 0..127
            float s = 0.f, d = 0.f;
            for (int o = 0; o < O_DIM; o++) {
                float w = W2[c * O_DIM + o];
                s += w * as2v[o];
                d += w * ad2v[o];
            }
            was2[c] = s; wad2[c] = d;
        }
        return;
    }
    int gid = blockIdx.x * 256 + threadIdx.x;
    const int stride = 32 * 256;
    for (int i = gid; i < N_NODES; i += stride) cnt[i] = 0;
    for (int i = gid; i < H_DIM * F_DIM; i += stride) {
        int n = i >> 8, k = i & 255;
        W1T[i] = f2bf(W1[k * H_DIM + n]);
    }
    for (int i = gid; i < O_DIM * H_DIM; i += stride) {
        int n = i >> 7, k = i & 127;
        W2T[i] = f2bf(W2[k * O_DIM + n]);
    }
}

// ---- per-edge a_e: 4-lane subgroups, edge-pair unroll; REP for attribution ----
__global__ __launch_bounds__(256) void k_edge_ae(
        const float* __restrict__ ea, const int* __restrict__ dst,
        const float* __restrict__ wv1, const float* __restrict__ wv2,
        float2* __restrict__ ae12, int* __restrict__ cnt) {
    int tid = threadIdx.x;
    int wave = tid >> 6, lane = tid & 63;
    int sub = lane & 3, eg = lane >> 2;
    float4 w1[4], w2[4];
#pragma unroll
    for (int j = 0; j < 4; j++) {
        w1[j] = ((const float4*)wv1)[sub * 4 + j];
        w2[j] = ((const float4*)wv2)[sub * 4 + j];
    }
    int e0 = ((blockIdx.x * 4 + wave) * 16 + eg) * 2;
    const int stride = EB * 128;
    for (int rep = 0; rep < REP; rep++) {
        asm volatile("" ::: "memory");   // forbid cross-rep value reuse
        for (int e = e0; e < N_EDGES; e += stride) {
            const float4* r0 = (const float4*)(ea + (size_t)e * ED_DIM + sub * 16);
            const float4* r1 = (const float4*)(ea + (size_t)(e + 1) * ED_DIM + sub * 16);
            float4 a0 = r0[0], a1 = r0[1], a2 = r0[2], a3 = r0[3];
            float4 b0 = r1[0], b1 = r1[1], b2 = r1[2], b3 = r1[3];
            float s1 = dot4(a0, w1[0]) + dot4(a1, w1[1]) + dot4(a2, w1[2]) + dot4(a3, w1[3]);
            float s2 = dot4(a0, w2[0]) + dot4(a1, w2[1]) + dot4(a2, w2[2]) + dot4(a3, w2[3]);
            float t1 = dot4(b0, w1[0]) + dot4(b1, w1[1]) + dot4(b2, w1[2]) + dot4(b3, w1[3]);
            float t2 = dot4(b0, w2[0]) + dot4(b1, w2[1]) + dot4(b2, w2[2]) + dot4(b3, w2[3]);
            s1 += __shfl_xor(s1, 1); s2 += __shfl_xor(s2, 1);
            t1 += __shfl_xor(t1, 1); t2 += __shfl_xor(t2, 1);
            s1 += __shfl_xor(s1, 2); s2 += __shfl_xor(s2, 2);
            t1 += __shfl_xor(t1, 2); t2 += __shfl_xor(t2, 2);
            if (sub == 0) {
                ae12[e] = make_float2(s1, s2);
                ae12[e + 1] = make_float2(t1, t2);
                if (rep == 0) {              // atomics are NOT idempotent
                    atomicAdd(&cnt[dst[e]], 1);
                    atomicAdd(&cnt[dst[e + 1]], 1);
                }
            }
        }
    }
}

// ======= MFMA GEMM layer 1: h1(bf16) = x@W1, fused a_s/a_d; REP for attribution =======
__global__ __launch_bounds__(256) void k_gemm1(const float* __restrict__ A,
        const unsigned short* __restrict__ BT,
        const float* __restrict__ asv, const float* __restrict__ adv,
        unsigned short* __restrict__ Hb, float* __restrict__ a_s, float* __restrict__ a_d, int M) {
    __shared__ unsigned short As[128 * 40];
    __shared__ unsigned short Bs[128 * 40];
    int tid = threadIdx.x;
    int wave = tid >> 6, lane = tid & 63;
    int q = lane >> 4, r = lane & 15;
    int bm0 = blockIdx.x * 128;
    int rr = tid >> 3;
    int kc = tid & 7;
    for (int rep = 0; rep < REP; rep++) {
        asm volatile("" ::: "memory");
        floatx4 acc[2][8];
#pragma unroll
        for (int a = 0; a < 2; a++)
#pragma unroll
            for (int b = 0; b < 8; b++) acc[a][b] = (floatx4){0.f, 0.f, 0.f, 0.f};

        for (int k0 = 0; k0 < 256; k0 += 32) {
            __syncthreads();   // protect As/Bs against previous iteration readers
#pragma unroll
            for (int i = 0; i < 4; i++) {
                int row = rr + 32 * i;
                int gr = bm0 + row;
                float4 v = make_float4(0.f, 0.f, 0.f, 0.f);
                if (gr < M) v = *(const float4*)(A + (size_t)gr * 256 + k0 + kc * 4);
                unsigned lo = (unsigned)f2bf(v.x) | ((unsigned)f2bf(v.y) << 16);
                unsigned hi = (unsigned)f2bf(v.z) | ((unsigned)f2bf(v.w) << 16);
                *(uint2*)&As[row * 40 + kc * 4] = make_uint2(lo, hi);
            }
#pragma unroll
            for (int i = 0; i < 2; i++) {
                int idx = tid + 256 * i;
                int n = idx >> 2, ck = idx & 3;
                *(uint4*)&Bs[n * 40 + ck * 8] = *(const uint4*)(BT + n * 256 + k0 + ck * 8);
            }
            __syncthreads();
            short8 af[2], bf[8];
#pragma unroll
            for (int rt = 0; rt < 2; rt++)
                af[rt] = *(const short8*)&As[(wave * 32 + rt * 16 + r) * 40 + q * 8];
#pragma unroll
            for (int nt = 0; nt < 8; nt++)
                bf[nt] = *(const short8*)&Bs[(nt * 16 + r) * 40 + q * 8];
#pragma unroll
            for (int rt = 0; rt < 2; rt++)
#pragma unroll
                for (int nt = 0; nt < 8; nt++)
                    acc[rt][nt] = __builtin_amdgcn_mfma_f32_16x16x32_bf16(af[rt], bf[nt], acc[rt][nt], 0, 0, 0);
        }
#pragma unroll
        for (int rt = 0; rt < 2; rt++) {
            int rowb = bm0 + wave * 32 + rt * 16 + q * 4;
            float ps[4] = {0.f, 0.f, 0.f, 0.f}, pd[4] = {0.f, 0.f, 0.f, 0.f};
#pragma unroll
            for (int nt = 0; nt < 8; nt++) {
                int col = nt * 16 + r;
                float av = asv[col], dv = adv[col];
#pragma unroll
                for (int reg = 0; reg < 4; reg++) {
                    float v = acc[rt][nt][reg];
                    if (rowb + reg < M) Hb[(size_t)(rowb + reg) * 128 + col] = f2bf(v);
                    ps[reg] += v * av;
                    pd[reg] += v * dv;
                }
            }
#pragma unroll
            for (int reg = 0; reg < 4; reg++) {
#pragma unroll
                for (int off = 1; off < 16; off <<= 1) {
                    ps[reg] += __shfl_xor(ps[reg], off);
                    pd[reg] += __shfl_xor(pd[reg], off);
                }
            }
            if (r == 0) {
#pragma unroll
                for (int reg = 0; reg < 4; reg++) {
                    if (rowb + reg < M) { a_s[rowb + reg] = ps[reg]; a_d[rowb + reg] = pd[reg]; }
                }
            }
        }
        __syncthreads();
    }
}

// ---------------- prefix-sum (CSR offsets), 2 dispatches ----------------
__global__ void k_scan1(const int* __restrict__ cnt, int* __restrict__ bsum, int n) {
    __shared__ int sh[256];
    int b = blockIdx.x, t = threadIdx.x;
    int base = b * 1024;
    int s = 0;
    for (int j = 0; j < 4; j++) {
        int idx = base + t * 4 + j;
        if (idx < n) s += cnt[idx];
    }
    sh[t] = s; __syncthreads();
    for (int o = 128; o > 0; o >>= 1) {
        if (t < o) sh[t] += sh[t + o];
        __syncthreads();
    }
    if (t == 0) bsum[b] = sh[0];
}

// per-block bsum prefix computed in-kernel (nb <= 64)
__global__ void k_scan3(const int* __restrict__ cnt, const int* __restrict__ bsum,
                        int* __restrict__ offs, int* __restrict__ cursor, int n, int nb) {
    __shared__ int sh[256];
    __shared__ int bpre_sh;
    int b = blockIdx.x, t = threadIdx.x;
    if (t < 64) {
        int v = (t < b) ? bsum[t] : 0;
#pragma unroll
        for (int o = 1; o < 64; o <<= 1) v += __shfl_xor(v, o);
        if (t == 0) bpre_sh = v;
    }
    int base = b * 1024;
    int v4[4]; int s = 0;
    for (int j = 0; j < 4; j++) {
        int idx = base + t * 4 + j;
        v4[j] = (idx < n) ? cnt[idx] : 0;
        s += v4[j];
    }
    sh[t] = s; __syncthreads();
    for (int o = 1; o < 256; o <<= 1) {
        int x = (t >= o) ? sh[t - o] : 0;
        __syncthreads();
        sh[t] += x;
        __syncthreads();
    }
    int texcl = sh[t] - s + bpre_sh;
    int run = 0;
    for (int j = 0; j < 4; j++) {
        int idx = base + t * 4 + j;
        if (idx < n) { offs[idx] = texcl + run; cursor[idx] = texcl + run; }
        run += v4[j];
    }
    if (b == nb - 1 && t == 255) offs[n] = bpre_sh + sh[255];
}

// scatter edges into CSR order; REP: atomic once, csr write repeated (idempotent)
__global__ __launch_bounds__(256) void k_scatter(const int* __restrict__ src, const int* __restrict__ dst,
                          const float2* __restrict__ ae12, const float* __restrict__ a_s1,
                          int* __restrict__ cursor, float4* __restrict__ csr) {
    int e = blockIdx.x * blockDim.x + threadIdx.x;
    if (e >= N_EDGES) return;
    int p = 0;
    for (int rep = 0; rep < REP; rep++) {
        asm volatile("" ::: "memory");
        int s = src[e];
        int d = dst[e];
        float2 a = ae12[e];
        float as = a_s1[s];
        if (rep == 0) p = atomicAdd(&cursor[d], 1);
        csr[p] = make_float4(__int_as_float(s), a.x, a.y, as);
    }
}

// ========== single-pass softmax agg C=128 (bf16 gather), fused a_s2/a_d2 ==========
template <bool RELU>
__global__ __launch_bounds__(256) void k_agg128(const unsigned short* __restrict__ h,
                         const float* __restrict__ a_s, const float* __restrict__ a_d,
                         const int* __restrict__ offs, const float4* __restrict__ csr,
                         const float* __restrict__ bias,
                         const float* __restrict__ was2, const float* __restrict__ wad2,
                         float* __restrict__ a_s2, float* __restrict__ a_d2,
                         float* __restrict__ out) {
    int wave = threadIdx.x >> 6, lane = threadIdx.x & 63;
    int i = blockIdx.x * 4 + wave;
    int r = lane & 15;       // channel group: channels r*8 .. r*8+7
    int g = lane >> 4;       // edge subgroup (4 subgroups of 16)
    int rs = offs[i], re = offs[i + 1];
    int deg = re - rs;
    float adl = a_d[i];
    float4 acc0 = {0.f, 0.f, 0.f, 0.f}, acc1 = {0.f, 0.f, 0.f, 0.f};
    float dsum = 0.f, sum_ae = 0.f;

#define P128(EL)                                                              \
    {                                                                         \
        float4 c = csr[EL];            /* uniform addr in subgroup: L1 bcast */\
        int s = __float_as_int(c.x);                                          \
        float aev = c.y;                                                      \
        float ex = __expf(leaky(c.w + adl + aev));                            \
        if (r == 0) { dsum += ex; sum_ae += aev; }                            \
        uint4 hv = *(const uint4*)(h + (size_t)s * 128 + r * 8);              \
        acc0.x += ex * bf2f_lo(hv.x); acc0.y += ex * bf2f_hi(hv.x);           \
        acc0.z += ex * bf2f_lo(hv.y); acc0.w += ex * bf2f_hi(hv.y);           \
        acc1.x += ex * bf2f_lo(hv.z); acc1.y += ex * bf2f_hi(hv.z);           \
        acc1.z += ex * bf2f_lo(hv.w); acc1.w += ex * bf2f_hi(hv.w);           \
    }

    int el = rs + g;
    for (; el + 4 < re; el += 8) { P128(el); P128(el + 4); }
    if (el < re) P128(el);
#undef P128

    // dsum/sum_ae nonzero only in lanes 0,16,32,48 -> FULL butterfly broadcast
#pragma unroll
    for (int o = 1; o < 64; o <<= 1) {
        dsum += __shfl_xor(dsum, o);
        sum_ae += __shfl_xor(sum_ae, o);
    }

    float loop_ae = sum_ae / (float)(deg > 1 ? deg : 1);
    float al = leaky(a_s[i] + adl + loop_ae);
    float exs = __expf(al);
    float* a0 = (float*)&acc0; float* a1 = (float*)&acc1;
#pragma unroll
    for (int c = 0; c < 4; c++) {
        a0[c] += __shfl_xor(a0[c], 16); a0[c] += __shfl_xor(a0[c], 32);
        a1[c] += __shfl_xor(a1[c], 16); a1[c] += __shfl_xor(a1[c], 32);
    }
    if (g == 0) {
        float inv = 1.0f / (dsum + exs + EPS_F);
        uint4 hv = *(const uint4*)(h + (size_t)i * 128 + r * 8);
        const float4* bp = (const float4*)bias;
        float4 b0 = bp[r * 2], b1 = bp[r * 2 + 1];
        float4 o0, o1;
        o0.x = (a0[0] + exs * bf2f_lo(hv.x)) * inv + b0.x;
        o0.y = (a0[1] + exs * bf2f_hi(hv.x)) * inv + b0.y;
        o0.z = (a0[2] + exs * bf2f_lo(hv.y)) * inv + b0.z;
        o0.w = (a0[3] + exs * bf2f_hi(hv.y)) * inv + b0.w;
        o1.x = (a1[0] + exs * bf2f_lo(hv.z)) * inv + b1.x;
        o1.y = (a1[1] + exs * bf2f_hi(hv.z)) * inv + b1.y;
        o1.z = (a1[2] + exs * bf2f_lo(hv.w)) * inv + b1.z;
        o1.w = (a1[3] + exs * bf2f_hi(hv.w)) * inv + b1.w;
        if (RELU) {
            o0.x = fmaxf(o0.x, 0.f); o0.y = fmaxf(o0.y, 0.f); o0.z = fmaxf(o0.z, 0.f); o0.w = fmaxf(o0.w, 0.f);
            o1.x = fmaxf(o1.x, 0.f); o1.y = fmaxf(o1.y, 0.f); o1.z = fmaxf(o1.z, 0.f); o1.w = fmaxf(o1.w, 0.f);
        }
        float4* op = (float4*)(out + (size_t)i * 128);
        op[r * 2] = o0;
        op[r * 2 + 1] = o1;
        // fused layer-2 attention scalars: a_s2 = x~ . (W2@att_src2), f32-exact
        float4 wsa = ((const float4*)was2)[r * 2], wsb = ((const float4*)was2)[r * 2 + 1];
        float4 wda = ((const float4*)wad2)[r * 2], wdb = ((const float4*)wad2)[r * 2 + 1];
        float ps = dot4(o0, wsa) + dot4(o1, wsb);
        float pd = dot4(o0, wda) + dot4(o1, wdb);
#pragma unroll
        for (int o = 1; o < 16; o <<= 1) {
            ps += __shfl_xor(ps, o);
            pd += __shfl_xor(pd, o);
        }
        if (r == 0) { a_s2[i] = ps; a_d2[i] = pd; }
    }
}

// =============== MFMA GEMM layer 2: h2(bf16) = relu(x1)@W2; REP ===============
__global__ __launch_bounds__(256) void k_gemm2(const float* __restrict__ A,
        const unsigned short* __restrict__ BT,
        unsigned short* __restrict__ Hb, int M) {
    __shared__ unsigned short As[128 * 40];
    __shared__ unsigned short Bs[32 * 40];
    int tid = threadIdx.x;
    int wave = tid >> 6, lane = tid & 63;
    int q = lane >> 4, r = lane & 15;
    int bm0 = blockIdx.x * 128;
    int rr = tid >> 3;
    int kc = tid & 7;
    for (int rep = 0; rep < REP; rep++) {
        asm volatile("" ::: "memory");
        floatx4 acc[2][2];
#pragma unroll
        for (int a = 0; a < 2; a++)
#pragma unroll
            for (int b = 0; b < 2; b++) acc[a][b] = (floatx4){0.f, 0.f, 0.f, 0.f};

        for (int k0 = 0; k0 < 128; k0 += 32) {
            __syncthreads();
#pragma unroll
            for (int i = 0; i < 4; i++) {
                int row = rr + 32 * i;
                int gr = bm0 + row;
                float4 v = make_float4(0.f, 0.f, 0.f, 0.f);
                if (gr < M) v = *(const float4*)(A + (size_t)gr * 128 + k0 + kc * 4);
                unsigned lo = (unsigned)f2bf(v.x) | ((unsigned)f2bf(v.y) << 16);
                unsigned hi = (unsigned)f2bf(v.z) | ((unsigned)f2bf(v.w) << 16);
                *(uint2*)&As[row * 40 + kc * 4] = make_uint2(lo, hi);
            }
            if (tid < 128) {
                int n = tid >> 2, ck = tid & 3;
                *(uint4*)&Bs[n * 40 + ck * 8] = *(const uint4*)(BT + n * 128 + k0 + ck * 8);
            }
            __syncthreads();
            short8 af[2], bf[2];
#pragma unroll
            for (int rt = 0; rt < 2; rt++)
                af[rt] = *(const short8*)&As[(wave * 32 + rt * 16 + r) * 40 + q * 8];
#pragma unroll
            for (int nt = 0; nt < 2; nt++)
                bf[nt] = *(const short8*)&Bs[(nt * 16 + r) * 40 + q * 8];
#pragma unroll
            for (int rt = 0; rt < 2; rt++)
#pragma unroll
                for (int nt = 0; nt < 2; nt++)
                    acc[rt][nt] = __builtin_amdgcn_mfma_f32_16x16x32_bf16(af[rt], bf[nt], acc[rt][nt], 0, 0, 0);
        }
#pragma unroll
        for (int rt = 0; rt < 2; rt++) {
            int rowb = bm0 + wave * 32 + rt * 16 + q * 4;
#pragma unroll
            for (int nt = 0; nt < 2; nt++) {
                int col = nt * 16 + r;
#pragma unroll
                for (int reg = 0; reg < 4; reg++) {
                    if (rowb + reg < M) Hb[(size_t)(rowb + reg) * 32 + col] = f2bf(acc[rt][nt][reg]);
                }
            }
        }
        __syncthreads();
    }
}

// ========== single-pass softmax agg C=32 (bf16 gather), 8-lane subgroups ==========
__global__ __launch_bounds__(256) void k_agg32(const unsigned short* __restrict__ h,
                        const float* __restrict__ a_s, const float* __restrict__ a_d,
                        const int* __restrict__ offs, const float4* __restrict__ csr,
                        const float* __restrict__ bias,
                        float* __restrict__ out) {
    int wave = threadIdx.x >> 6, lane = threadIdx.x & 63;
    int i = blockIdx.x * 4 + wave;
    int r = lane & 7;        // channels r*4 .. r*4+3
    int g = lane >> 3;       // 8 edge subgroups
    int rs = offs[i], re = offs[i + 1];
    int deg = re - rs;
    float adl = a_d[i];
    float4 acc = {0.f, 0.f, 0.f, 0.f};
    float dsum = 0.f, sum_ae = 0.f;

#define P32(EL)                                                               \
    {                                                                         \
        float4 c = csr[EL];                                                   \
        int s = __float_as_int(c.x);                                          \
        float aev = c.z;                                                      \
        float ex = __expf(leaky(a_s[s] + adl + aev));                         \
        if (r == 0) { dsum += ex; sum_ae += aev; }                            \
        uint2 hv = *(const uint2*)(h + (size_t)s * 32 + r * 4);               \
        acc.x += ex * bf2f_lo(hv.x); acc.y += ex * bf2f_hi(hv.x);             \
        acc.z += ex * bf2f_lo(hv.y); acc.w += ex * bf2f_hi(hv.y);             \
    }

    int el = rs + g;
    for (; el + 8 < re; el += 16) { P32(el); P32(el + 8); }
    if (el < re) P32(el);
#undef P32

#pragma unroll
    for (int o = 1; o < 64; o <<= 1) {
        dsum += __shfl_xor(dsum, o);
        sum_ae += __shfl_xor(sum_ae, o);
    }

    float loop_ae = sum_ae / (float)(deg > 1 ? deg : 1);
    float al = leaky(a_s[i] + adl + loop_ae);
    float exs = __expf(al);
#pragma unroll
    for (int o = 8; o < 64; o <<= 1) {
        acc.x += __shfl_xor(acc.x, o); acc.y += __shfl_xor(acc.y, o);
        acc.z += __shfl_xor(acc.z, o); acc.w += __shfl_xor(acc.w, o);
    }
    if (g == 0) {
        float inv = 1.0f / (dsum + exs + EPS_F);
        uint2 hv = *(const uint2*)(h + (size_t)i * 32 + r * 4);
        float4 bv = ((const float4*)bias)[r];
        float4 ov;
        ov.x = (acc.x + exs * bf2f_lo(hv.x)) * inv + bv.x;
        ov.y = (acc.y + exs * bf2f_hi(hv.x)) * inv + bv.y;
        ov.z = (acc.z + exs * bf2f_lo(hv.y)) * inv + bv.z;
        ov.w = (acc.w + exs * bf2f_hi(hv.y)) * inv + bv.w;
        ((float4*)(out + (size_t)i * 32))[r] = ov;
    }
}

extern "C" void kernel_launch(void* const* d_in, const int* in_sizes, int n_in,
                              void* d_out, int out_size, void* d_ws, size_t ws_size,
                              hipStream_t stream) {
    const float* x    = (const float*)d_in[0];
    const int* ei     = (const int*)d_in[1];
    const float* ea   = (const float*)d_in[2];
    const float* W1   = (const float*)d_in[3];
    const float* as1v = (const float*)d_in[4];
    const float* ad1v = (const float*)d_in[5];
    const float* We1  = (const float*)d_in[6];
    const float* aev1 = (const float*)d_in[7];
    const float* b1   = (const float*)d_in[8];
    const float* W2   = (const float*)d_in[9];
    const float* as2v = (const float*)d_in[10];
    const float* ad2v = (const float*)d_in[11];
    const float* We2  = (const float*)d_in[12];
    const float* aev2 = (const float*)d_in[13];
    const float* b2   = (const float*)d_in[14];

    const int* src = ei;
    const int* dst = ei + N_EDGES;

    char* w = (char*)d_ws;
    size_t off = 0;
    auto alloc = [&](size_t bytes) -> void* {
        void* p = w + off;
        off += bytes;
        off = (off + 255) & ~(size_t)255;
        return p;
    };
    unsigned short* h1b = (unsigned short*)alloc((size_t)N_NODES * H_DIM * 2);
    unsigned short* h2b = (unsigned short*)alloc((size_t)N_NODES * O_DIM * 2);
    float2* ae12   = (float2*)alloc((size_t)N_EDGES * 8);
    int* cnt       = (int*)alloc((size_t)N_NODES * 4);
    int* offs      = (int*)alloc((size_t)(N_NODES + 1) * 4);
    int* cursor    = (int*)alloc((size_t)N_NODES * 4);
    float4* csr    = (float4*)alloc((size_t)N_EDGES * 16);
    int* bsum      = (int*)alloc(64 * 4);
    float* wv1     = (float*)alloc(64 * 4);
    float* wv2     = (float*)alloc(64 * 4);
    float* was2    = (float*)alloc(128 * 4);
    float* wad2    = (float*)alloc(128 * 4);
    float* a_s1    = (float*)alloc((size_t)N_NODES * 4);
    float* a_d1    = (float*)alloc((size_t)N_NODES * 4);
    float* a_s2    = (float*)alloc((size_t)N_NODES * 4);
    float* a_d2    = (float*)alloc((size_t)N_NODES * 4);
    unsigned short* W1T = (unsigned short*)alloc((size_t)H_DIM * F_DIM * 2);
    unsigned short* W2T = (unsigned short*)alloc((size_t)O_DIM * H_DIM * 2);

    k_prep<<<33, 256, 0, stream>>>(We1, aev1, We2, aev2, wv1, wv2, W1, W2,
                                   as2v, ad2v, was2, wad2, W1T, W2T, cnt);

    k_edge_ae<<<EB, 256, 0, stream>>>(ea, dst, wv1, wv2, ae12, cnt);

    k_gemm1<<<(N_NODES + 127) / 128, 256, 0, stream>>>(x, W1T, as1v, ad1v,
                                                       h1b, a_s1, a_d1, N_NODES);

    int nb = (N_NODES + 1023) / 1024;   // 49 (<= 64)
    k_scan1<<<nb, 256, 0, stream>>>(cnt, bsum, N_NODES);
    k_scan3<<<nb, 256, 0, stream>>>(cnt, bsum, offs, cursor, N_NODES, nb);

    k_scatter<<<(N_EDGES + 255) / 256, 256, 0, stream>>>(src, dst, ae12, a_s1,
                                                         cursor, csr);

    float* out = (float*)d_out;                       // [N, O]
    float* h_out = out + (size_t)N_NODES * O_DIM;     // [N, H] = relu(x1)

    k_agg128<true><<<(N_NODES + 3) / 4, 256, 0, stream>>>(h1b, a_s1, a_d1, offs,
                                                          csr, b1, was2, wad2,
                                                          a_s2, a_d2, h_out);

    k_gemm2<<<(N_NODES + 127) / 128, 256, 0, stream>>>(h_out, W2T, h2b, N_NODES);

    k_agg32<<<(N_NODES + 3) / 4, 256, 0, stream>>>(h2b, a_s2, a_d2, offs,
                                                   csr, b2, out);
}

// Round 9
// 372.162 us; speedup vs baseline: 1.1283x; 1.0813x over previous
//
#include <hip/hip_runtime.h>

#define N_NODES 50000
#define N_EDGES 500000
#define F_DIM 256
#define ED_DIM 64
#define H_DIM 128
#define O_DIM 32
#define NEG_SLOPE 0.2f
#define EPS_F 1e-16f

#define EB 2048          // edge kernel blocks

typedef __attribute__((ext_vector_type(8))) short short8;
typedef __attribute__((ext_vector_type(4))) float floatx4;

__device__ __forceinline__ unsigned short f2bf(float f) {
    union { float f; unsigned u; } c; c.f = f;
    unsigned u = c.u;
    return (unsigned short)((u + 0x7fffu + ((u >> 16) & 1u)) >> 16);
}
__device__ __forceinline__ float bf2f_lo(unsigned u) { return __uint_as_float(u << 16); }
__device__ __forceinline__ float bf2f_hi(unsigned u) { return __uint_as_float(u & 0xffff0000u); }
__device__ __forceinline__ float leaky(float a) { return a > 0.f ? a : a * NEG_SLOPE; }
__device__ __forceinline__ float dot4(float4 a, float4 b) {
    return a.x * b.x + a.y * b.y + a.z * b.z + a.w * b.w;
}

// ---- prep: wv = We@a_edge, was2/wad2 = W2@att2, W transposes, zero cnt ----
__global__ void k_prep(const float* __restrict__ We1, const float* __restrict__ aev1,
                       const float* __restrict__ We2, const float* __restrict__ aev2,
                       float* __restrict__ wv1, float* __restrict__ wv2,
                       const float* __restrict__ W1, const float* __restrict__ W2,
                       const float* __restrict__ as2v, const float* __restrict__ ad2v,
                       float* __restrict__ was2, float* __restrict__ wad2,
                       unsigned short* __restrict__ W1T, unsigned short* __restrict__ W2T,
                       int* __restrict__ cnt) {
    if (blockIdx.x == 32) {
        int t = threadIdx.x;
        if (t < 64) {
            float s = 0.f;
            for (int c = 0; c < H_DIM; c++) s += We1[t * H_DIM + c] * aev1[c];
            wv1[t] = s;
        } else if (t < 128) {
            int k = t - 64;
            float s = 0.f;
            for (int c = 0; c < O_DIM; c++) s += We2[k * O_DIM + c] * aev2[c];
            wv2[k] = s;
        } else {
            int c = t - 128;   // 0..127
            float s = 0.f, d = 0.f;
            for (int o = 0; o < O_DIM; o++) {
                float w = W2[c * O_DIM + o];
                s += w * as2v[o];
                d += w * ad2v[o];
            }
            was2[c] = s; wad2[c] = d;
        }
        return;
    }
    int gid = blockIdx.x * 256 + threadIdx.x;
    const int stride = 32 * 256;
    for (int i = gid; i < N_NODES; i += stride) cnt[i] = 0;
    for (int i = gid; i < H_DIM * F_DIM; i += stride) {
        int n = i >> 8, k = i & 255;
        W1T[i] = f2bf(W1[k * H_DIM + n]);
    }
    for (int i = gid; i < O_DIM * H_DIM; i += stride) {
        int n = i >> 7, k = i & 127;
        W2T[i] = f2bf(W2[k * O_DIM + n]);
    }
}

// ---- per-edge a_e: 4-lane subgroups, edge-pair unroll (8 loads in flight/lane) ----
__global__ __launch_bounds__(256) void k_edge_ae(
        const float* __restrict__ ea, const int* __restrict__ dst,
        const float* __restrict__ wv1, const float* __restrict__ wv2,
        float2* __restrict__ ae12, int* __restrict__ cnt) {
    int tid = threadIdx.x;
    int wave = tid >> 6, lane = tid & 63;
    int sub = lane & 3, eg = lane >> 2;
    float4 w1[4], w2[4];
#pragma unroll
    for (int j = 0; j < 4; j++) {
        w1[j] = ((const float4*)wv1)[sub * 4 + j];
        w2[j] = ((const float4*)wv2)[sub * 4 + j];
    }
    int e0 = ((blockIdx.x * 4 + wave) * 16 + eg) * 2;
    const int stride = EB * 128;
    for (int e = e0; e < N_EDGES; e += stride) {
        const float4* r0 = (const float4*)(ea + (size_t)e * ED_DIM + sub * 16);
        const float4* r1 = (const float4*)(ea + (size_t)(e + 1) * ED_DIM + sub * 16);
        float4 a0 = r0[0], a1 = r0[1], a2 = r0[2], a3 = r0[3];
        float4 b0 = r1[0], b1 = r1[1], b2 = r1[2], b3 = r1[3];
        float s1 = dot4(a0, w1[0]) + dot4(a1, w1[1]) + dot4(a2, w1[2]) + dot4(a3, w1[3]);
        float s2 = dot4(a0, w2[0]) + dot4(a1, w2[1]) + dot4(a2, w2[2]) + dot4(a3, w2[3]);
        float t1 = dot4(b0, w1[0]) + dot4(b1, w1[1]) + dot4(b2, w1[2]) + dot4(b3, w1[3]);
        float t2 = dot4(b0, w2[0]) + dot4(b1, w2[1]) + dot4(b2, w2[2]) + dot4(b3, w2[3]);
        s1 += __shfl_xor(s1, 1); s2 += __shfl_xor(s2, 1);
        t1 += __shfl_xor(t1, 1); t2 += __shfl_xor(t2, 1);
        s1 += __shfl_xor(s1, 2); s2 += __shfl_xor(s2, 2);
        t1 += __shfl_xor(t1, 2); t2 += __shfl_xor(t2, 2);
        if (sub == 0) {
            ae12[e] = make_float2(s1, s2);
            ae12[e + 1] = make_float2(t1, t2);
            atomicAdd(&cnt[dst[e]], 1);
            atomicAdd(&cnt[dst[e + 1]], 1);
        }
    }
}

// ======= MFMA GEMM layer 1: h1(bf16) = x@W1, fused a_s/a_d =======
__global__ __launch_bounds__(256) void k_gemm1(const float* __restrict__ A,
        const unsigned short* __restrict__ BT,
        const float* __restrict__ asv, const float* __restrict__ adv,
        unsigned short* __restrict__ Hb, float* __restrict__ a_s, float* __restrict__ a_d, int M) {
    __shared__ unsigned short As[128 * 40];
    __shared__ unsigned short Bs[128 * 40];
    int tid = threadIdx.x;
    int wave = tid >> 6, lane = tid & 63;
    int q = lane >> 4, r = lane & 15;
    int bm0 = blockIdx.x * 128;
    floatx4 acc[2][8];
#pragma unroll
    for (int a = 0; a < 2; a++)
#pragma unroll
        for (int b = 0; b < 8; b++) acc[a][b] = (floatx4){0.f, 0.f, 0.f, 0.f};

    int rr = tid >> 3;
    int kc = tid & 7;
    for (int k0 = 0; k0 < 256; k0 += 32) {
#pragma unroll
        for (int i = 0; i < 4; i++) {
            int row = rr + 32 * i;
            int gr = bm0 + row;
            float4 v = make_float4(0.f, 0.f, 0.f, 0.f);
            if (gr < M) v = *(const float4*)(A + (size_t)gr * 256 + k0 + kc * 4);
            unsigned lo = (unsigned)f2bf(v.x) | ((unsigned)f2bf(v.y) << 16);
            unsigned hi = (unsigned)f2bf(v.z) | ((unsigned)f2bf(v.w) << 16);
            *(uint2*)&As[row * 40 + kc * 4] = make_uint2(lo, hi);
        }
#pragma unroll
        for (int i = 0; i < 2; i++) {
            int idx = tid + 256 * i;
            int n = idx >> 2, ck = idx & 3;
            *(uint4*)&Bs[n * 40 + ck * 8] = *(const uint4*)(BT + n * 256 + k0 + ck * 8);
        }
        __syncthreads();
        short8 af[2], bf[8];
#pragma unroll
        for (int rt = 0; rt < 2; rt++)
            af[rt] = *(const short8*)&As[(wave * 32 + rt * 16 + r) * 40 + q * 8];
#pragma unroll
        for (int nt = 0; nt < 8; nt++)
            bf[nt] = *(const short8*)&Bs[(nt * 16 + r) * 40 + q * 8];
#pragma unroll
        for (int rt = 0; rt < 2; rt++)
#pragma unroll
            for (int nt = 0; nt < 8; nt++)
                acc[rt][nt] = __builtin_amdgcn_mfma_f32_16x16x32_bf16(af[rt], bf[nt], acc[rt][nt], 0, 0, 0);
        __syncthreads();
    }
#pragma unroll
    for (int rt = 0; rt < 2; rt++) {
        int rowb = bm0 + wave * 32 + rt * 16 + q * 4;
        float ps[4] = {0.f, 0.f, 0.f, 0.f}, pd[4] = {0.f, 0.f, 0.f, 0.f};
#pragma unroll
        for (int nt = 0; nt < 8; nt++) {
            int col = nt * 16 + r;
            float av = asv[col], dv = adv[col];
#pragma unroll
            for (int reg = 0; reg < 4; reg++) {
                float v = acc[rt][nt][reg];
                if (rowb + reg < M) Hb[(size_t)(rowb + reg) * 128 + col] = f2bf(v);
                ps[reg] += v * av;
                pd[reg] += v * dv;
            }
        }
#pragma unroll
        for (int reg = 0; reg < 4; reg++) {
#pragma unroll
            for (int off = 1; off < 16; off <<= 1) {
                ps[reg] += __shfl_xor(ps[reg], off);
                pd[reg] += __shfl_xor(pd[reg], off);
            }
        }
        if (r == 0) {
#pragma unroll
            for (int reg = 0; reg < 4; reg++) {
                if (rowb + reg < M) { a_s[rowb + reg] = ps[reg]; a_d[rowb + reg] = pd[reg]; }
            }
        }
    }
}

// ---------------- prefix-sum (CSR offsets), 2 dispatches ----------------
__global__ void k_scan1(const int* __restrict__ cnt, int* __restrict__ bsum, int n) {
    __shared__ int sh[256];
    int b = blockIdx.x, t = threadIdx.x;
    int base = b * 1024;
    int s = 0;
    for (int j = 0; j < 4; j++) {
        int idx = base + t * 4 + j;
        if (idx < n) s += cnt[idx];
    }
    sh[t] = s; __syncthreads();
    for (int o = 128; o > 0; o >>= 1) {
        if (t < o) sh[t] += sh[t + o];
        __syncthreads();
    }
    if (t == 0) bsum[b] = sh[0];
}

// per-block bsum prefix computed in-kernel (nb <= 64)
__global__ void k_scan3(const int* __restrict__ cnt, const int* __restrict__ bsum,
                        int* __restrict__ offs, int* __restrict__ cursor, int n, int nb) {
    __shared__ int sh[256];
    __shared__ int bpre_sh;
    int b = blockIdx.x, t = threadIdx.x;
    if (t < 64) {
        int v = (t < b) ? bsum[t] : 0;
#pragma unroll
        for (int o = 1; o < 64; o <<= 1) v += __shfl_xor(v, o);
        if (t == 0) bpre_sh = v;
    }
    int base = b * 1024;
    int v4[4]; int s = 0;
    for (int j = 0; j < 4; j++) {
        int idx = base + t * 4 + j;
        v4[j] = (idx < n) ? cnt[idx] : 0;
        s += v4[j];
    }
    sh[t] = s; __syncthreads();
    for (int o = 1; o < 256; o <<= 1) {
        int x = (t >= o) ? sh[t - o] : 0;
        __syncthreads();
        sh[t] += x;
        __syncthreads();
    }
    int texcl = sh[t] - s + bpre_sh;
    int run = 0;
    for (int j = 0; j < 4; j++) {
        int idx = base + t * 4 + j;
        if (idx < n) { offs[idx] = texcl + run; cursor[idx] = texcl + run; }
        run += v4[j];
    }
    if (b == nb - 1 && t == 255) offs[n] = bpre_sh + sh[255];
}

// scatter edges into CSR order; packed entry {src, ae1, ae2, a_s1[src]} (one 16B line)
__global__ __launch_bounds__(256) void k_scatter(const int* __restrict__ src, const int* __restrict__ dst,
                          const float2* __restrict__ ae12, const float* __restrict__ a_s1,
                          int* __restrict__ cursor, float4* __restrict__ csr) {
    int e = blockIdx.x * blockDim.x + threadIdx.x;
    if (e >= N_EDGES) return;
    int s = src[e];
    int d = dst[e];
    float2 a = ae12[e];
    float as = a_s1[s];
    int p = atomicAdd(&cursor[d], 1);
    csr[p] = make_float4(__int_as_float(s), a.x, a.y, as);
}

// ========== single-pass softmax agg C=128 (bf16 gather), fused a_s2/a_d2 ==========
template <bool RELU>
__global__ __launch_bounds__(256) void k_agg128(const unsigned short* __restrict__ h,
                         const float* __restrict__ a_s, const float* __restrict__ a_d,
                         const int* __restrict__ offs, const float4* __restrict__ csr,
                         const float* __restrict__ bias,
                         const float* __restrict__ was2, const float* __restrict__ wad2,
                         float* __restrict__ a_s2, float* __restrict__ a_d2,
                         float* __restrict__ out) {
    int wave = threadIdx.x >> 6, lane = threadIdx.x & 63;
    int i = blockIdx.x * 4 + wave;
    int r = lane & 15;       // channel group: channels r*8 .. r*8+7
    int g = lane >> 4;       // edge subgroup (4 subgroups of 16)
    int rs = offs[i], re = offs[i + 1];
    int deg = re - rs;
    float adl = a_d[i];
    float4 acc0 = {0.f, 0.f, 0.f, 0.f}, acc1 = {0.f, 0.f, 0.f, 0.f};
    float dsum = 0.f, sum_ae = 0.f;

#define P128(EL)                                                              \
    {                                                                         \
        float4 c = csr[EL];            /* uniform addr in subgroup: L1 bcast */\
        int s = __float_as_int(c.x);                                          \
        float aev = c.y;                                                      \
        float ex = __expf(leaky(c.w + adl + aev));                            \
        if (r == 0) { dsum += ex; sum_ae += aev; }                            \
        uint4 hv = *(const uint4*)(h + (size_t)s * 128 + r * 8);              \
        acc0.x += ex * bf2f_lo(hv.x); acc0.y += ex * bf2f_hi(hv.x);           \
        acc0.z += ex * bf2f_lo(hv.y); acc0.w += ex * bf2f_hi(hv.y);           \
        acc1.x += ex * bf2f_lo(hv.z); acc1.y += ex * bf2f_hi(hv.z);           \
        acc1.z += ex * bf2f_lo(hv.w); acc1.w += ex * bf2f_hi(hv.w);           \
    }

    int el = rs + g;
    for (; el + 4 < re; el += 8) { P128(el); P128(el + 4); }
    if (el < re) P128(el);
#undef P128

    // dsum/sum_ae nonzero only in lanes 0,16,32,48 -> FULL butterfly broadcast
#pragma unroll
    for (int o = 1; o < 64; o <<= 1) {
        dsum += __shfl_xor(dsum, o);
        sum_ae += __shfl_xor(sum_ae, o);
    }

    float loop_ae = sum_ae / (float)(deg > 1 ? deg : 1);
    float al = leaky(a_s[i] + adl + loop_ae);
    float exs = __expf(al);
    float* a0 = (float*)&acc0; float* a1 = (float*)&acc1;
#pragma unroll
    for (int c = 0; c < 4; c++) {
        a0[c] += __shfl_xor(a0[c], 16); a0[c] += __shfl_xor(a0[c], 32);
        a1[c] += __shfl_xor(a1[c], 16); a1[c] += __shfl_xor(a1[c], 32);
    }
    if (g == 0) {
        float inv = 1.0f / (dsum + exs + EPS_F);
        uint4 hv = *(const uint4*)(h + (size_t)i * 128 + r * 8);
        const float4* bp = (const float4*)bias;
        float4 b0 = bp[r * 2], b1 = bp[r * 2 + 1];
        float4 o0, o1;
        o0.x = (a0[0] + exs * bf2f_lo(hv.x)) * inv + b0.x;
        o0.y = (a0[1] + exs * bf2f_hi(hv.x)) * inv + b0.y;
        o0.z = (a0[2] + exs * bf2f_lo(hv.y)) * inv + b0.z;
        o0.w = (a0[3] + exs * bf2f_hi(hv.y)) * inv + b0.w;
        o1.x = (a1[0] + exs * bf2f_lo(hv.z)) * inv + b1.x;
        o1.y = (a1[1] + exs * bf2f_hi(hv.z)) * inv + b1.y;
        o1.z = (a1[2] + exs * bf2f_lo(hv.w)) * inv + b1.z;
        o1.w = (a1[3] + exs * bf2f_hi(hv.w)) * inv + b1.w;
        if (RELU) {
            o0.x = fmaxf(o0.x, 0.f); o0.y = fmaxf(o0.y, 0.f); o0.z = fmaxf(o0.z, 0.f); o0.w = fmaxf(o0.w, 0.f);
            o1.x = fmaxf(o1.x, 0.f); o1.y = fmaxf(o1.y, 0.f); o1.z = fmaxf(o1.z, 0.f); o1.w = fmaxf(o1.w, 0.f);
        }
        float4* op = (float4*)(out + (size_t)i * 128);
        op[r * 2] = o0;
        op[r * 2 + 1] = o1;
        // fused layer-2 attention scalars: a_s2 = x~ . (W2@att_src2), f32-exact
        float4 wsa = ((const float4*)was2)[r * 2], wsb = ((const float4*)was2)[r * 2 + 1];
        float4 wda = ((const float4*)wad2)[r * 2], wdb = ((const float4*)wad2)[r * 2 + 1];
        float ps = dot4(o0, wsa) + dot4(o1, wsb);
        float pd = dot4(o0, wda) + dot4(o1, wdb);
#pragma unroll
        for (int o = 1; o < 16; o <<= 1) {
            ps += __shfl_xor(ps, o);
            pd += __shfl_xor(pd, o);
        }
        if (r == 0) { a_s2[i] = ps; a_d2[i] = pd; }
    }
}

// =============== MFMA GEMM layer 2: h2(bf16) = relu(x1)@W2 ===============
__global__ __launch_bounds__(256) void k_gemm2(const float* __restrict__ A,
        const unsigned short* __restrict__ BT,
        unsigned short* __restrict__ Hb, int M) {
    __shared__ unsigned short As[128 * 40];
    __shared__ unsigned short Bs[32 * 40];
    int tid = threadIdx.x;
    int wave = tid >> 6, lane = tid & 63;
    int q = lane >> 4, r = lane & 15;
    int bm0 = blockIdx.x * 128;
    floatx4 acc[2][2];
#pragma unroll
    for (int a = 0; a < 2; a++)
#pragma unroll
        for (int b = 0; b < 2; b++) acc[a][b] = (floatx4){0.f, 0.f, 0.f, 0.f};

    int rr = tid >> 3;
    int kc = tid & 7;
    for (int k0 = 0; k0 < 128; k0 += 32) {
#pragma unroll
        for (int i = 0; i < 4; i++) {
            int row = rr + 32 * i;
            int gr = bm0 + row;
            float4 v = make_float4(0.f, 0.f, 0.f, 0.f);
            if (gr < M) v = *(const float4*)(A + (size_t)gr * 128 + k0 + kc * 4);
            unsigned lo = (unsigned)f2bf(v.x) | ((unsigned)f2bf(v.y) << 16);
            unsigned hi = (unsigned)f2bf(v.z) | ((unsigned)f2bf(v.w) << 16);
            *(uint2*)&As[row * 40 + kc * 4] = make_uint2(lo, hi);
        }
        if (tid < 128) {
            int n = tid >> 2, ck = tid & 3;
            *(uint4*)&Bs[n * 40 + ck * 8] = *(const uint4*)(BT + n * 128 + k0 + ck * 8);
        }
        __syncthreads();
        short8 af[2], bf[2];
#pragma unroll
        for (int rt = 0; rt < 2; rt++)
            af[rt] = *(const short8*)&As[(wave * 32 + rt * 16 + r) * 40 + q * 8];
#pragma unroll
        for (int nt = 0; nt < 2; nt++)
            bf[nt] = *(const short8*)&Bs[(nt * 16 + r) * 40 + q * 8];
#pragma unroll
        for (int rt = 0; rt < 2; rt++)
#pragma unroll
            for (int nt = 0; nt < 2; nt++)
                acc[rt][nt] = __builtin_amdgcn_mfma_f32_16x16x32_bf16(af[rt], bf[nt], acc[rt][nt], 0, 0, 0);
        __syncthreads();
    }
#pragma unroll
    for (int rt = 0; rt < 2; rt++) {
        int rowb = bm0 + wave * 32 + rt * 16 + q * 4;
#pragma unroll
        for (int nt = 0; nt < 2; nt++) {
            int col = nt * 16 + r;
#pragma unroll
            for (int reg = 0; reg < 4; reg++) {
                if (rowb + reg < M) Hb[(size_t)(rowb + reg) * 32 + col] = f2bf(acc[rt][nt][reg]);
            }
        }
    }
}

// ========== single-pass softmax agg C=32 (bf16 gather), 8-lane subgroups ==========
__global__ __launch_bounds__(256) void k_agg32(const unsigned short* __restrict__ h,
                        const float* __restrict__ a_s, const float* __restrict__ a_d,
                        const int* __restrict__ offs, const float4* __restrict__ csr,
                        const float* __restrict__ bias,
                        float* __restrict__ out) {
    int wave = threadIdx.x >> 6, lane = threadIdx.x & 63;
    int i = blockIdx.x * 4 + wave;
    int r = lane & 7;        // channels r*4 .. r*4+3
    int g = lane >> 3;       // 8 edge subgroups
    int rs = offs[i], re = offs[i + 1];
    int deg = re - rs;
    float adl = a_d[i];
    float4 acc = {0.f, 0.f, 0.f, 0.f};
    float dsum = 0.f, sum_ae = 0.f;

#define P32(EL)                                                               \
    {                                                                         \
        float4 c = csr[EL];                                                   \
        int s = __float_as_int(c.x);                                          \
        float aev = c.z;                                                      \
        float ex = __expf(leaky(a_s[s] + adl + aev));                         \
        if (r == 0) { dsum += ex; sum_ae += aev; }                            \
        uint2 hv = *(const uint2*)(h + (size_t)s * 32 + r * 4);               \
        acc.x += ex * bf2f_lo(hv.x); acc.y += ex * bf2f_hi(hv.x);             \
        acc.z += ex * bf2f_lo(hv.y); acc.w += ex * bf2f_hi(hv.y);             \
    }

    int el = rs + g;
    for (; el + 8 < re; el += 16) { P32(el); P32(el + 8); }
    if (el < re) P32(el);
#undef P32

#pragma unroll
    for (int o = 1; o < 64; o <<= 1) {
        dsum += __shfl_xor(dsum, o);
        sum_ae += __shfl_xor(sum_ae, o);
    }

    float loop_ae = sum_ae / (float)(deg > 1 ? deg : 1);
    float al = leaky(a_s[i] + adl + loop_ae);
    float exs = __expf(al);
#pragma unroll
    for (int o = 8; o < 64; o <<= 1) {
        acc.x += __shfl_xor(acc.x, o); acc.y += __shfl_xor(acc.y, o);
        acc.z += __shfl_xor(acc.z, o); acc.w += __shfl_xor(acc.w, o);
    }
    if (g == 0) {
        float inv = 1.0f / (dsum + exs + EPS_F);
        uint2 hv = *(const uint2*)(h + (size_t)i * 32 + r * 4);
        float4 bv = ((const float4*)bias)[r];
        float4 ov;
        ov.x = (acc.x + exs * bf2f_lo(hv.x)) * inv + bv.x;
        ov.y = (acc.y + exs * bf2f_hi(hv.x)) * inv + bv.y;
        ov.z = (acc.z + exs * bf2f_lo(hv.y)) * inv + bv.z;
        ov.w = (acc.w + exs * bf2f_hi(hv.y)) * inv + bv.w;
        ((float4*)(out + (size_t)i * 32))[r] = ov;
    }
}

extern "C" void kernel_launch(void* const* d_in, const int* in_sizes, int n_in,
                              void* d_out, int out_size, void* d_ws, size_t ws_size,
                              hipStream_t stream) {
    const float* x    = (const float*)d_in[0];
    const int* ei     = (const int*)d_in[1];
    const float* ea   = (const float*)d_in[2];
    const float* W1   = (const float*)d_in[3];
    const float* as1v = (const float*)d_in[4];
    const float* ad1v = (const float*)d_in[5];
    const float* We1  = (const float*)d_in[6];
    const float* aev1 = (const float*)d_in[7];
    const float* b1   = (const float*)d_in[8];
    const float* W2   = (const float*)d_in[9];
    const float* as2v = (const float*)d_in[10];
    const float* ad2v = (const float*)d_in[11];
    const float* We2  = (const float*)d_in[12];
    const float* aev2 = (const float*)d_in[13];
    const float* b2   = (const float*)d_in[14];

    const int* src = ei;
    const int* dst = ei + N_EDGES;

    char* w = (char*)d_ws;
    size_t off = 0;
    auto alloc = [&](size_t bytes) -> void* {
        void* p = w + off;
        off += bytes;
        off = (off + 255) & ~(size_t)255;
        return p;
    };
    unsigned short* h1b = (unsigned short*)alloc((size_t)N_NODES * H_DIM * 2);
    unsigned short* h2b = (unsigned short*)alloc((size_t)N_NODES * O_DIM * 2);
    float2* ae12   = (float2*)alloc((size_t)N_EDGES * 8);
    int* cnt       = (int*)alloc((size_t)N_NODES * 4);
    int* offs      = (int*)alloc((size_t)(N_NODES + 1) * 4);
    int* cursor    = (int*)alloc((size_t)N_NODES * 4);
    float4* csr    = (float4*)alloc((size_t)N_EDGES * 16);
    int* bsum      = (int*)alloc(64 * 4);
    float* wv1     = (float*)alloc(64 * 4);
    float* wv2     = (float*)alloc(64 * 4);
    float* was2    = (float*)alloc(128 * 4);
    float* wad2    = (float*)alloc(128 * 4);
    float* a_s1    = (float*)alloc((size_t)N_NODES * 4);
    float* a_d1    = (float*)alloc((size_t)N_NODES * 4);
    float* a_s2    = (float*)alloc((size_t)N_NODES * 4);
    float* a_d2    = (float*)alloc((size_t)N_NODES * 4);
    unsigned short* W1T = (unsigned short*)alloc((size_t)H_DIM * F_DIM * 2);
    unsigned short* W2T = (unsigned short*)alloc((size_t)O_DIM * H_DIM * 2);

    k_prep<<<33, 256, 0, stream>>>(We1, aev1, We2, aev2, wv1, wv2, W1, W2,
                                   as2v, ad2v, was2, wad2, W1T, W2T, cnt);

    k_edge_ae<<<EB, 256, 0, stream>>>(ea, dst, wv1, wv2, ae12, cnt);

    k_gemm1<<<(N_NODES + 127) / 128, 256, 0, stream>>>(x, W1T, as1v, ad1v,
                                                       h1b, a_s1, a_d1, N_NODES);

    int nb = (N_NODES + 1023) / 1024;   // 49 (<= 64)
    k_scan1<<<nb, 256, 0, stream>>>(cnt, bsum, N_NODES);
    k_scan3<<<nb, 256, 0, stream>>>(cnt, bsum, offs, cursor, N_NODES, nb);

    k_scatter<<<(N_EDGES + 255) / 256, 256, 0, stream>>>(src, dst, ae12, a_s1,
                                                         cursor, csr);

    float* out = (float*)d_out;                       // [N, O]
    float* h_out = out + (size_t)N_NODES * O_DIM;     // [N, H] = relu(x1)

    k_agg128<true><<<(N_NODES + 3) / 4, 256, 0, stream>>>(h1b, a_s1, a_d1, offs,
                                                          csr, b1, was2, wad2,
                                                          a_s2, a_d2, h_out);

    k_gemm2<<<(N_NODES + 127) / 128, 256, 0, stream>>>(h_out, W2T, h2b, N_NODES);

    k_agg32<<<(N_NODES + 3) / 4, 256, 0, stream>>>(h2b, a_s2, a_d2, offs,
                                                   csr, b2, out);
}